// Round 1
// baseline (1490.647 us; speedup 1.0000x reference)
//
#include <hip/hip_runtime.h>
#include <math.h>

#define NN 100000
#define NE 1600000
#define EA (NE + NN)
#define D 64
#define DE 32
#define NB_SCAN ((NN + 255) / 256)   // 391

__device__ __forceinline__ int rfl(int v){ return __builtin_amdgcn_readfirstlane(v); }

__global__ __launch_bounds__(256) void k_deg(const int* __restrict__ dst, int* __restrict__ deg){
  int i = blockIdx.x*256 + threadIdx.x;
  if (i < NE) atomicAdd(&deg[dst[i]], 1);
}

__global__ __launch_bounds__(256) void k_scan_a(const int* __restrict__ deg, int* __restrict__ bsum){
  __shared__ int sh[256];
  int tid = threadIdx.x;
  int i = blockIdx.x*256 + tid;
  sh[tid] = (i < NN) ? (deg[i] + 1) : 0;
  __syncthreads();
  for (int s = 128; s > 0; s >>= 1){
    if (tid < s) sh[tid] += sh[tid+s];
    __syncthreads();
  }
  if (tid == 0) bsum[blockIdx.x] = sh[0];
}

__global__ __launch_bounds__(512) void k_scan_b(int* __restrict__ bsum, int* __restrict__ rowptr){
  __shared__ int tmp[512];
  int tid = threadIdx.x;
  int v = (tid < NB_SCAN) ? bsum[tid] : 0;
  tmp[tid] = v;
  __syncthreads();
  for (int off = 1; off < 512; off <<= 1){
    int t = (tid >= off) ? tmp[tid-off] : 0;
    __syncthreads();
    tmp[tid] += t;
    __syncthreads();
  }
  if (tid < NB_SCAN) bsum[tid] = tmp[tid] - v;   // exclusive block offsets
  if (tid == 511) rowptr[NN] = tmp[511];         // total = EA
}

__global__ __launch_bounds__(256) void k_scan_c(const int* __restrict__ deg, const int* __restrict__ bsum,
                                                int* __restrict__ rowptr, int* __restrict__ cursor){
  __shared__ int tmp[256];
  int tid = threadIdx.x;
  int i = blockIdx.x*256 + tid;
  int v = (i < NN) ? (deg[i] + 1) : 0;
  tmp[tid] = v;
  __syncthreads();
  for (int off = 1; off < 256; off <<= 1){
    int t = (tid >= off) ? tmp[tid-off] : 0;
    __syncthreads();
    tmp[tid] += t;
    __syncthreads();
  }
  if (i < NN){
    int excl = tmp[tid] - v + bsum[blockIdx.x];
    rowptr[i] = excl;
    cursor[i] = excl;
  }
}

__global__ __launch_bounds__(256) void k_scatter(const int* __restrict__ dst, int* __restrict__ cursor,
                                                 int* __restrict__ slot){
  int i = blockIdx.x*256 + threadIdx.x;
  if (i < EA){
    int d = (i < NE) ? dst[i] : (i - NE);
    int pos = atomicAdd(&cursor[d], 1);
    slot[pos] = i;
  }
}

// loop_attr[n][k] = sum of edge_attr over real incoming edges / max(deg,1)
__global__ __launch_bounds__(256) void k_loopattr(const int* __restrict__ rowptr, const int* __restrict__ slot,
                                                  const float* __restrict__ eattr, const int* __restrict__ deg,
                                                  float* __restrict__ loop_attr){
  int lane = threadIdx.x & 63;
  int wpb = blockDim.x >> 6;
  int wid = blockIdx.x * wpb + (threadIdx.x >> 6);
  int nw = gridDim.x * wpb;
  int k = lane & 31;
  for (int n0 = wid; n0 < NN; n0 += nw){
    int n = rfl(n0);
    int st = rowptr[n], en = rowptr[n+1];
    float acc = 0.f;
    for (int i = st; i < en; ++i){
      int eid = slot[i];
      if (eid < NE) acc += eattr[(size_t)eid*DE + k];
    }
    float dg = (float)max(deg[n], 1);
    if (lane < 32) loop_attr[(size_t)n*DE + k] = acc / dg;
  }
}

// xl[n][j] = b[j] + sum_k x[n][k] * W[k][j] ; one wave per node, W column in VGPRs
__global__ __launch_bounds__(256) void k_lin(const float* __restrict__ xin, const float* __restrict__ W,
                                             const float* __restrict__ b, float* __restrict__ xl){
  int lane = threadIdx.x & 63;
  int wpb = blockDim.x >> 6;
  int wid = blockIdx.x * wpb + (threadIdx.x >> 6);
  int nw = gridDim.x * wpb;
  float wcol[D];
  #pragma unroll
  for (int kk = 0; kk < D; ++kk) wcol[kk] = W[kk*D + lane];
  float bj = b[lane];
  for (int n0 = wid; n0 < NN; n0 += nw){
    int n = rfl(n0);
    const float* xr = xin + (size_t)n*D;
    float acc = bj;
    #pragma unroll
    for (int kk = 0; kk < D; ++kk) acc = fmaf(xr[kk], wcol[kk], acc);
    xl[(size_t)n*D + lane] = acc;
  }
}

// logits[e] = att . leaky(xl[src] + xl[dst] + ea@We) ; one wave per augmented edge
__global__ __launch_bounds__(256) void k_edge(const int* __restrict__ srcp, const int* __restrict__ dstp,
                                              const float* __restrict__ eattr, const float* __restrict__ loop_attr,
                                              const float* __restrict__ We, const float* __restrict__ att,
                                              const float* __restrict__ xl, float* __restrict__ logits){
  int lane = threadIdx.x & 63;
  int wpb = blockDim.x >> 6;
  int wid = blockIdx.x * wpb + (threadIdx.x >> 6);
  int nw = gridDim.x * wpb;
  float wecol[DE];
  #pragma unroll
  for (int kk = 0; kk < DE; ++kk) wecol[kk] = We[kk*D + lane];
  float attj = att[lane];
  for (int e0 = wid; e0 < EA; e0 += nw){
    int e = rfl(e0);
    int s, d; const float* ea;
    if (e < NE){ s = srcp[e]; d = dstp[e]; ea = eattr + (size_t)e*DE; }
    else { s = e - NE; d = s; ea = loop_attr + (size_t)(e - NE)*DE; }
    float t = 0.f;
    #pragma unroll
    for (int kk = 0; kk < DE; ++kk) t = fmaf(ea[kk], wecol[kk], t);
    float m = xl[(size_t)s*D + lane] + xl[(size_t)d*D + lane] + t;
    m = (m > 0.f) ? m : 0.2f*m;
    float c = m * attj;
    #pragma unroll
    for (int off = 32; off > 0; off >>= 1) c += __shfl_xor(c, off, 64);
    if (lane == 0) logits[e] = c;
  }
}

// out[n][j] = bias[j] + sum_e alpha_e * xl[src_e][j]  via online softmax over CSR segment
__global__ __launch_bounds__(256) void k_node(const int* __restrict__ rowptr, const int* __restrict__ slot,
                                              const int* __restrict__ srcp, const float* __restrict__ logits,
                                              const float* __restrict__ xl, const float* __restrict__ bias,
                                              float* __restrict__ outp){
  int lane = threadIdx.x & 63;
  int wpb = blockDim.x >> 6;
  int wid = blockIdx.x * wpb + (threadIdx.x >> 6);
  int nw = gridDim.x * wpb;
  float bj = bias[lane];
  for (int n0 = wid; n0 < NN; n0 += nw){
    int n = rfl(n0);
    int st = rowptr[n], en = rowptr[n+1];
    float m = -INFINITY, den = 0.f, acc = 0.f;
    for (int i = st; i < en; ++i){
      int eid = slot[i];
      int s = (eid < NE) ? srcp[eid] : n;
      float lg = logits[eid];
      float mn = fmaxf(m, lg);
      float sc = __expf(m - mn);
      float p  = __expf(lg - mn);
      den = den * sc + p;
      acc = acc * sc + p * xl[(size_t)s*D + lane];
      m = mn;
    }
    outp[(size_t)n*D + lane] = acc/den + bj;
  }
}

extern "C" void kernel_launch(void* const* d_in, const int* in_sizes, int n_in,
                              void* d_out, int out_size, void* d_ws, size_t ws_size,
                              hipStream_t stream){
  const float* x     = (const float*)d_in[0];
  const int*   ei    = (const int*)d_in[1];
  const float* eattr = (const float*)d_in[2];
  const float* W1    = (const float*)d_in[3];
  const float* b1    = (const float*)d_in[4];
  const float* We1   = (const float*)d_in[5];
  const float* att1  = (const float*)d_in[6];
  const float* bias1 = (const float*)d_in[7];
  const float* W2    = (const float*)d_in[8];
  const float* b2    = (const float*)d_in[9];
  const float* We2   = (const float*)d_in[10];
  const float* att2  = (const float*)d_in[11];
  const float* bias2 = (const float*)d_in[12];
  const int* srcp = ei;
  const int* dstp = ei + NE;
  float* out = (float*)d_out;

  char* p = (char*)d_ws;
  size_t off = 0;
  auto alloc = [&](size_t bytes)->char*{
    char* r = p + off; off = (off + bytes + 255) & ~(size_t)255; return r;
  };
  int* deg      = (int*)alloc((size_t)NN*4);
  int* rowptr   = (int*)alloc((size_t)(NN+1)*4);
  int* cursor   = (int*)alloc((size_t)NN*4);
  int* bsum     = (int*)alloc(512*4);
  int* slot     = (int*)alloc((size_t)EA*4);
  float* loop_attr = (float*)alloc((size_t)NN*DE*4);
  float* xl     = (float*)alloc((size_t)NN*D*4);
  float* logits = (float*)alloc((size_t)EA*4);
  float* h      = (float*)alloc((size_t)NN*D*4);

  hipMemsetAsync(deg, 0, (size_t)NN*4, stream);
  k_deg    <<<(NE+255)/256, 256, 0, stream>>>(dstp, deg);
  k_scan_a <<<NB_SCAN, 256, 0, stream>>>(deg, bsum);
  k_scan_b <<<1, 512, 0, stream>>>(bsum, rowptr);
  k_scan_c <<<NB_SCAN, 256, 0, stream>>>(deg, bsum, rowptr, cursor);
  k_scatter<<<(EA+255)/256, 256, 0, stream>>>(dstp, cursor, slot);
  k_loopattr<<<2048, 256, 0, stream>>>(rowptr, slot, eattr, deg, loop_attr);

  // layer 1
  k_lin  <<<2048, 256, 0, stream>>>(x, W1, b1, xl);
  k_edge <<<4096, 256, 0, stream>>>(srcp, dstp, eattr, loop_attr, We1, att1, xl, logits);
  k_node <<<2048, 256, 0, stream>>>(rowptr, slot, srcp, logits, xl, bias1, h);

  // layer 2
  k_lin  <<<2048, 256, 0, stream>>>(h, W2, b2, xl);
  k_edge <<<4096, 256, 0, stream>>>(srcp, dstp, eattr, loop_attr, We2, att2, xl, logits);
  k_node <<<2048, 256, 0, stream>>>(rowptr, slot, srcp, logits, xl, bias2, out);
}

// Round 2
// 1031.439 us; speedup vs baseline: 1.4452x; 1.4452x over previous
//
#include <hip/hip_runtime.h>
#include <math.h>

#define NN 100000
#define NE 1600000
#define D 64
#define DE 32
#define NB_SCAN ((NN + 255) / 256)   // 391

__device__ __forceinline__ int rfl(int v){ return __builtin_amdgcn_readfirstlane(v); }

__device__ __forceinline__ float wave_sum(float c){
  #pragma unroll
  for (int off = 32; off > 0; off >>= 1) c += __shfl_xor(c, off, 64);
  return c;
}

__global__ __launch_bounds__(256) void k_deg(const int* __restrict__ dst, int* __restrict__ deg){
  int i = blockIdx.x*256 + threadIdx.x;
  if (i < NE) atomicAdd(&deg[dst[i]], 1);
}

__global__ __launch_bounds__(256) void k_scan_a(const int* __restrict__ deg, int* __restrict__ bsum){
  __shared__ int sh[256];
  int tid = threadIdx.x;
  int i = blockIdx.x*256 + tid;
  sh[tid] = (i < NN) ? deg[i] : 0;
  __syncthreads();
  for (int s = 128; s > 0; s >>= 1){
    if (tid < s) sh[tid] += sh[tid+s];
    __syncthreads();
  }
  if (tid == 0) bsum[blockIdx.x] = sh[0];
}

__global__ __launch_bounds__(512) void k_scan_b(int* __restrict__ bsum, int* __restrict__ rowptr){
  __shared__ int tmp[512];
  int tid = threadIdx.x;
  int v = (tid < NB_SCAN) ? bsum[tid] : 0;
  tmp[tid] = v;
  __syncthreads();
  for (int off = 1; off < 512; off <<= 1){
    int t = (tid >= off) ? tmp[tid-off] : 0;
    __syncthreads();
    tmp[tid] += t;
    __syncthreads();
  }
  if (tid < NB_SCAN) bsum[tid] = tmp[tid] - v;   // exclusive block offsets
  if (tid == 511) rowptr[NN] = tmp[511];         // total = NE
}

__global__ __launch_bounds__(256) void k_scan_c(const int* __restrict__ deg, const int* __restrict__ bsum,
                                                int* __restrict__ rowptr, int* __restrict__ cursor){
  __shared__ int tmp[256];
  int tid = threadIdx.x;
  int i = blockIdx.x*256 + tid;
  int v = (i < NN) ? deg[i] : 0;
  tmp[tid] = v;
  __syncthreads();
  for (int off = 1; off < 256; off <<= 1){
    int t = (tid >= off) ? tmp[tid-off] : 0;
    __syncthreads();
    tmp[tid] += t;
    __syncthreads();
  }
  if (i < NN){
    int excl = tmp[tid] - v + bsum[blockIdx.x];
    rowptr[i] = excl;
    cursor[i] = excl;
  }
}

// slot[pos] = edge id, ssrc[pos] = source node of that edge (pre-resolved)
__global__ __launch_bounds__(256) void k_scatter(const int* __restrict__ srcp, const int* __restrict__ dstp,
                                                 int* __restrict__ cursor,
                                                 int* __restrict__ slot, int* __restrict__ ssrc){
  int i = blockIdx.x*256 + threadIdx.x;
  if (i < NE){
    int d = dstp[i];
    int pos = atomicAdd(&cursor[d], 1);
    slot[pos] = i;
    ssrc[pos] = srcp[i];
  }
}

// xl[n][j] = b[j] + sum_k x[n][k] * W[k][j] ; one wave per node, W column in VGPRs
__global__ __launch_bounds__(256) void k_lin(const float* __restrict__ xin, const float* __restrict__ W,
                                             const float* __restrict__ b, float* __restrict__ xl){
  int lane = threadIdx.x & 63;
  int wpb = blockDim.x >> 6;
  int wid = blockIdx.x * wpb + (threadIdx.x >> 6);
  int nw = gridDim.x * wpb;
  float wcol[D];
  #pragma unroll
  for (int kk = 0; kk < D; ++kk) wcol[kk] = W[kk*D + lane];
  float bj = b[lane];
  for (int n0 = wid; n0 < NN; n0 += nw){
    int n = rfl(n0);
    const float* xr = xin + (size_t)n*D;
    float acc = bj;
    #pragma unroll
    for (int kk = 0; kk < D; ++kk) acc = fmaf(xr[kk], wcol[kk], acc);
    xl[(size_t)n*D + lane] = acc;
  }
}

// Fused per-destination GATv2: logits + softmax + weighted sum in one pass.
// Self-loop handled analytically: t_self = mean(t_e) by linearity of ea@We.
__global__ __launch_bounds__(256) void k_fused(const int* __restrict__ rowptr, const int* __restrict__ slot,
                                               const int* __restrict__ ssrc, const float* __restrict__ eattr,
                                               const float* __restrict__ We, const float* __restrict__ att,
                                               const float* __restrict__ xl, const float* __restrict__ bias,
                                               float* __restrict__ outp){
  int lane = threadIdx.x & 63;
  int wpb = blockDim.x >> 6;
  int wid = blockIdx.x * wpb + (threadIdx.x >> 6);
  int nw = gridDim.x * wpb;
  float wecol[DE];
  #pragma unroll
  for (int kk = 0; kk < DE; ++kk) wecol[kk] = We[kk*D + lane];
  float attj = att[lane];
  float bj = bias[lane];
  for (int n0 = wid; n0 < NN; n0 += nw){
    int n = rfl(n0);
    int st = rowptr[n], en = rowptr[n+1];
    float xd = xl[(size_t)n*D + lane];
    float den = 0.f, acc = 0.f, tsum = 0.f;
    int i = st;
    for (; i + 2 <= en; i += 2){
      int e0 = slot[i],  e1 = slot[i+1];
      int s0 = ssrc[i],  s1 = ssrc[i+1];
      const float* ea0 = eattr + (size_t)e0*DE;
      const float* ea1 = eattr + (size_t)e1*DE;
      float xs0 = xl[(size_t)s0*D + lane];
      float xs1 = xl[(size_t)s1*D + lane];
      float t0 = 0.f, t1 = 0.f;
      #pragma unroll
      for (int kk = 0; kk < DE; ++kk){
        t0 = fmaf(ea0[kk], wecol[kk], t0);
        t1 = fmaf(ea1[kk], wecol[kk], t1);
      }
      tsum += t0 + t1;
      float m0 = xs0 + xd + t0;
      float m1 = xs1 + xd + t1;
      m0 = (m0 > 0.f) ? m0 : 0.2f*m0;
      m1 = (m1 > 0.f) ? m1 : 0.2f*m1;
      float c0 = m0 * attj;
      float c1 = m1 * attj;
      #pragma unroll
      for (int off = 32; off > 0; off >>= 1){
        c0 += __shfl_xor(c0, off, 64);
        c1 += __shfl_xor(c1, off, 64);
      }
      float p0 = __expf(c0), p1 = __expf(c1);
      den += p0 + p1;
      acc = fmaf(p0, xs0, acc);
      acc = fmaf(p1, xs1, acc);
    }
    if (i < en){
      int e0 = slot[i];
      int s0 = ssrc[i];
      const float* ea0 = eattr + (size_t)e0*DE;
      float xs0 = xl[(size_t)s0*D + lane];
      float t0 = 0.f;
      #pragma unroll
      for (int kk = 0; kk < DE; ++kk) t0 = fmaf(ea0[kk], wecol[kk], t0);
      tsum += t0;
      float m0 = xs0 + xd + t0;
      m0 = (m0 > 0.f) ? m0 : 0.2f*m0;
      float p0 = __expf(wave_sum(m0 * attj));
      den += p0;
      acc = fmaf(p0, xs0, acc);
    }
    // self loop: ea = mean of incoming eattr  ->  t = tsum / max(deg,1)
    float degf = (float)(en - st);
    float ts = tsum / fmaxf(degf, 1.f);
    float ms = xd + xd + ts;
    ms = (ms > 0.f) ? ms : 0.2f*ms;
    float ps = __expf(wave_sum(ms * attj));
    den += ps;
    acc = fmaf(ps, xd, acc);
    outp[(size_t)n*D + lane] = acc/den + bj;
  }
}

extern "C" void kernel_launch(void* const* d_in, const int* in_sizes, int n_in,
                              void* d_out, int out_size, void* d_ws, size_t ws_size,
                              hipStream_t stream){
  const float* x     = (const float*)d_in[0];
  const int*   ei    = (const int*)d_in[1];
  const float* eattr = (const float*)d_in[2];
  const float* W1    = (const float*)d_in[3];
  const float* b1    = (const float*)d_in[4];
  const float* We1   = (const float*)d_in[5];
  const float* att1  = (const float*)d_in[6];
  const float* bias1 = (const float*)d_in[7];
  const float* W2    = (const float*)d_in[8];
  const float* b2    = (const float*)d_in[9];
  const float* We2   = (const float*)d_in[10];
  const float* att2  = (const float*)d_in[11];
  const float* bias2 = (const float*)d_in[12];
  const int* srcp = ei;
  const int* dstp = ei + NE;
  float* out = (float*)d_out;

  char* p = (char*)d_ws;
  size_t off = 0;
  auto alloc = [&](size_t bytes)->char*{
    char* r = p + off; off = (off + bytes + 255) & ~(size_t)255; return r;
  };
  int* deg      = (int*)alloc((size_t)NN*4);
  int* rowptr   = (int*)alloc((size_t)(NN+1)*4);
  int* cursor   = (int*)alloc((size_t)NN*4);
  int* bsum     = (int*)alloc(512*4);
  int* slot     = (int*)alloc((size_t)NE*4);
  int* ssrc     = (int*)alloc((size_t)NE*4);
  float* xl     = (float*)alloc((size_t)NN*D*4);
  float* h      = (float*)alloc((size_t)NN*D*4);

  hipMemsetAsync(deg, 0, (size_t)NN*4, stream);
  k_deg    <<<(NE+255)/256, 256, 0, stream>>>(dstp, deg);
  k_scan_a <<<NB_SCAN, 256, 0, stream>>>(deg, bsum);
  k_scan_b <<<1, 512, 0, stream>>>(bsum, rowptr);
  k_scan_c <<<NB_SCAN, 256, 0, stream>>>(deg, bsum, rowptr, cursor);
  k_scatter<<<(NE+255)/256, 256, 0, stream>>>(srcp, dstp, cursor, slot, ssrc);

  // layer 1
  k_lin   <<<2048, 256, 0, stream>>>(x, W1, b1, xl);
  k_fused <<<2048, 256, 0, stream>>>(rowptr, slot, ssrc, eattr, We1, att1, xl, bias1, h);

  // layer 2
  k_lin   <<<2048, 256, 0, stream>>>(h, W2, b2, xl);
  k_fused <<<2048, 256, 0, stream>>>(rowptr, slot, ssrc, eattr, We2, att2, xl, bias2, out);
}